// Round 2
// baseline (157.745 us; speedup 1.0000x reference)
//
#include <hip/hip_runtime.h>
#include <hip/hip_bf16.h>
#include <math.h>

// Problem: TOTAL=16M fp32 y/mu/std; idx int32 [200,100].
// q[i] = sum_j ((y[idx]-mu[idx])/std[idx])^2 ;
// out = KL(N(mean(q), var(q,ddof=1)) || N(K, 2K)).
//
// Latency-bound random gather + tiny reduction. Single fused kernel:
// 200 blocks x 128 thr; each block computes q_i, accumulates sum/sumsq via
// device-scope float atomics; last-arriving block (atomic counter) finalizes.
// Single-pass variance: q ~ 100 +- 14 so cancellation error on var is ~1e-5
// relative -> ~1e-6 on KL. Counter/accumulators live in d_ws, zeroed by a
// 12-byte hipMemsetAsync (graph-capture legal).

#define NUM_SAMPLES 200
#define KDOF 100

struct Accum {
    float sum;
    float sumsq;
    unsigned int count;
};

__global__ void __launch_bounds__(128) fused_chi2_kl_kernel(
        const float* __restrict__ y, const float* __restrict__ mu,
        const float* __restrict__ sd, const int* __restrict__ idx,
        float* __restrict__ out, Accum* __restrict__ acc) {
    const int i = blockIdx.x;   // sample
    const int j = threadIdx.x;  // dof lane

    float term = 0.0f;
    if (j < KDOF) {
        const int id = idx[i * KDOF + j];
        const float d = (y[id] - mu[id]) / sd[id];
        term = d * d;
    }
    // full 64-lane wave reduction
    for (int off = 32; off > 0; off >>= 1)
        term += __shfl_down(term, off, 64);

    __shared__ float partial[2];
    if ((j & 63) == 0) partial[j >> 6] = term;
    __syncthreads();

    if (j == 0) {
        const float q = partial[0] + partial[1];
        atomicAdd(&acc->sum, q);
        atomicAdd(&acc->sumsq, q * q);
        __threadfence();  // release: sum/sumsq visible before count bump
        const unsigned int old = atomicAdd(&acc->count, 1u);
        if (old == NUM_SAMPLES - 1) {
            __threadfence();  // acquire side
            // read through atomics -> device-coherent path (cross-XCD safe)
            const float s  = atomicAdd(&acc->sum, 0.0f);
            const float ss = atomicAdd(&acc->sumsq, 0.0f);
            const float n = (float)NUM_SAMPLES;
            const float mean = s / n;
            const float var = (ss - n * mean * mean) / (n - 1.0f);
            const float k = (float)KDOF;
            const float two_k = 2.0f * k;
            const float dm = mean - k;
            out[0] = 0.5f * logf(two_k / var)
                   + (var + dm * dm) / (2.0f * two_k) - 0.5f;
        }
    }
}

extern "C" void kernel_launch(void* const* d_in, const int* in_sizes, int n_in,
                              void* d_out, int out_size, void* d_ws, size_t ws_size,
                              hipStream_t stream) {
    const float* y   = (const float*)d_in[0];
    const float* mu  = (const float*)d_in[1];
    const float* sd  = (const float*)d_in[2];
    const int*   idx = (const int*)d_in[3];
    float* out = (float*)d_out;
    Accum* acc = (Accum*)d_ws;

    hipMemsetAsync(acc, 0, sizeof(Accum), stream);
    fused_chi2_kl_kernel<<<NUM_SAMPLES, 128, 0, stream>>>(y, mu, sd, idx, out, acc);
}

// Round 3
// 150.652 us; speedup vs baseline: 1.0471x; 1.0471x over previous
//
#include <hip/hip_runtime.h>
#include <hip/hip_bf16.h>
#include <math.h>

// Problem: TOTAL=16M fp32 y/mu/std; idx int32 [200,100].
// q[i] = sum_j ((y[idx]-mu[idx])/std[idx])^2 ;
// out = KL(N(mean(q), var(q,ddof=1)) || N(K, 2K)).
//
// Latency-bound random gather + tiny reduction. Timed window is dominated
// (~95%) by fixed harness restore traffic (3x64MB input copies + 268MB ws
// poison ~= 140-150us); our kernels are ~5us. Best-measured structure:
//   k1: 200 blocks x 64 thr (1 wave) -> q[i] into d_ws  (lane j covers dofs j, j+64)
//   k2: 1 block x 256 thr -> two-pass mean/var -> KL scalar

#define NUM_SAMPLES 200
#define KDOF 100

__device__ __forceinline__ float wave_reduce_sum(float v) {
    for (int off = 32; off > 0; off >>= 1)
        v += __shfl_down(v, off, 64);
    return v;
}

__global__ void __launch_bounds__(64) compute_q_kernel(
        const float* __restrict__ y, const float* __restrict__ mu,
        const float* __restrict__ sd, const int* __restrict__ idx,
        float* __restrict__ q) {
    const int i = blockIdx.x;   // sample
    const int j = threadIdx.x;  // lane, covers dofs j and j+64

    // two independent gathers per lane -> same latency chain as one
    const int id0 = idx[i * KDOF + j];
    float term = 0.0f;
    {
        const float d = (y[id0] - mu[id0]) / sd[id0];
        term = d * d;
    }
    if (j + 64 < KDOF) {
        const int id1 = idx[i * KDOF + j + 64];
        const float d = (y[id1] - mu[id1]) / sd[id1];
        term += d * d;
    }
    term = wave_reduce_sum(term);
    if (j == 0) q[i] = term;
}

__global__ void __launch_bounds__(256) finalize_kernel(
        const float* __restrict__ q, float* __restrict__ out) {
    const int t = threadIdx.x;
    const int wave = t >> 6;
    const int lane = t & 63;
    __shared__ float lds[4];
    __shared__ float s_mean;

    const float v = (t < NUM_SAMPLES) ? q[t] : 0.0f;

    // pass 1: mean
    float s = wave_reduce_sum(v);
    if (lane == 0) lds[wave] = s;
    __syncthreads();
    if (t == 0) {
        s_mean = (lds[0] + lds[1] + lds[2] + lds[3]) / (float)NUM_SAMPLES;
    }
    __syncthreads();
    const float mean = s_mean;

    // pass 2: sum of squared deviations (ddof=1)
    const float d = (t < NUM_SAMPLES) ? (v - mean) : 0.0f;
    float ss = wave_reduce_sum(d * d);
    __syncthreads();
    if (lane == 0) lds[wave] = ss;
    __syncthreads();
    if (t == 0) {
        const float var = (lds[0] + lds[1] + lds[2] + lds[3]) / (float)(NUM_SAMPLES - 1);
        const float k = (float)KDOF;
        const float two_k = 2.0f * k;
        const float dm = mean - k;
        out[0] = 0.5f * logf(two_k / var) + (var + dm * dm) / (2.0f * two_k) - 0.5f;
    }
}

extern "C" void kernel_launch(void* const* d_in, const int* in_sizes, int n_in,
                              void* d_out, int out_size, void* d_ws, size_t ws_size,
                              hipStream_t stream) {
    const float* y   = (const float*)d_in[0];
    const float* mu  = (const float*)d_in[1];
    const float* sd  = (const float*)d_in[2];
    const int*   idx = (const int*)d_in[3];
    float* out = (float*)d_out;
    float* q   = (float*)d_ws;  // 200 floats scratch, fully rewritten each call

    compute_q_kernel<<<NUM_SAMPLES, 64, 0, stream>>>(y, mu, sd, idx, q);
    finalize_kernel<<<1, 256, 0, stream>>>(q, out);
}